// Round 12
// baseline (445.478 us; speedup 1.0000x reference)
//
#include <hip/hip_runtime.h>
#include <cstdint>
#include <cstddef>

// Dtypes PROVEN fp32 (R2 bf16-read -> NaN; R4 fp32-read -> pass, absmax 0.0078).
#define N_NODES 8192
#define FIN 256
#define FOUT 128
#define JS 8                  // j slices (partial softmax, merged in fin_kernel)
#define JW (N_NODES / JS)     // 1024 columns per slice
#define KCH (JW / 32)         // 32 k-chunks of 32 cols per wave
#define LOG2E 1.4426950408889634f

typedef __attribute__((ext_vector_type(8))) short bf16x8;
typedef __attribute__((ext_vector_type(4))) float f32x4;

__device__ __forceinline__ float bf2f(unsigned short u) {
    union { unsigned int i; float f; } v; v.i = ((unsigned int)u) << 16; return v.f;
}
__device__ __forceinline__ unsigned short f2bf(float f) {
    union { float f; unsigned int i; } v; v.f = f;
    unsigned int r = (v.i + 0x7FFFu + ((v.i >> 16) & 1u)) >> 16;
    return (unsigned short)r;
}
__device__ __forceinline__ unsigned int pack_bf16(float a, float b) {
    return (unsigned)f2bf(a) | ((unsigned)f2bf(b) << 16);
}

// whB fragment-order layout: tile (kb, fb) holds Wh[j=kb*32+quad*8+e][f=fb*16+sl]
// at element ((kb*8+fb)*512 + (quad*16+sl)*8 + e) -> a wave's B-load is one
// contiguous 1 KB burst.
__device__ __forceinline__ size_t whb_idx(int j, int f) {
    return ((size_t)((j >> 5) * 8 + (f >> 4)) << 9) + (((j >> 3) & 3) << 7)
         + ((f & 15) << 3) + (j & 7);
}

// ---------------- Kernel P: pack adj (int32 0/1) -> bitmask ------------------
// Row r, u64 word w covers cols [w*64, w*64+64), bit b <-> col w*64+b.
// (Little-endian u8 view: byte col>>3, bit col&7.) Long sequential streams +
// 64 independent loads in flight per wave -> near-peak HBM rate (R8: ~45 us).
__global__ __launch_bounds__(256) void pack_kernel(const int* __restrict__ adj,
                                                   unsigned long long* __restrict__ bits) {
    const int t = threadIdx.x;
    const int lane = t & 63;
    const int wv = t >> 6;
    const int wid = blockIdx.x * 4 + wv;            // 0..4095
#pragma unroll
    for (int pass = 0; pass < 2; ++pass) {
        const int row = wid + pass * 4096;
        const int* ar = adj + (size_t)row * N_NODES;
        unsigned long long k0 = 0, k1 = 0;
#pragma unroll
        for (int seg = 0; seg < 64; ++seg) {        // cols [0, 4096)
            unsigned long long m = __ballot(ar[seg * 64 + lane] > 0);
            if (lane == seg) k0 = m;
        }
#pragma unroll
        for (int seg = 0; seg < 64; ++seg) {        // cols [4096, 8192)
            unsigned long long m = __ballot(ar[4096 + seg * 64 + lane] > 0);
            if (lane == seg) k1 = m;
        }
        unsigned long long* br = bits + (size_t)row * 128;
        br[lane] = k0;                               // coalesced 512 B/wave
        br[64 + lane] = k1;
    }
}

// ---------------- Kernel A: whB = fragment-ordered bf16 (h @ W^T) -------------
__global__ __launch_bounds__(256) void wh_kernel(const float* __restrict__ h,
                                                 const float* __restrict__ W,
                                                 unsigned short* __restrict__ whB) {
    __shared__ float hT[64][FIN + 5];   // stride 261 (odd)
    const int t = threadIdx.x;
    const int i0 = blockIdx.x * 64;
    const int f0 = blockIdx.y * 32;
#pragma unroll
    for (int c = 0; c < 16; ++c) {       // 64x256 floats, float4-coalesced
        int chunk = c * 256 + t;
        int row = chunk >> 6, col = (chunk & 63) * 4;
        f32x4 v = *(const f32x4*)&h[(size_t)(i0 + row) * FIN + col];
        hT[row][col] = v[0]; hT[row][col + 1] = v[1];
        hT[row][col + 2] = v[2]; hT[row][col + 3] = v[3];
    }
    __syncthreads();
    const int lane = t & 63;
    const int fb8 = __builtin_amdgcn_readfirstlane(f0 + (t >> 6) * 8); // wave -> 8 f
    const float* w0 = W + (size_t)fb8 * FIN;
    float acc[8] = {0.f, 0.f, 0.f, 0.f, 0.f, 0.f, 0.f, 0.f};
    for (int k = 0; k < FIN; k += 4) {
        float h0 = hT[lane][k],     h1 = hT[lane][k + 1];
        float h2 = hT[lane][k + 2], h3 = hT[lane][k + 3];
#pragma unroll
        for (int c = 0; c < 8; ++c) {
            const float* wr = w0 + c * FIN;   // uniform -> s_load
            acc[c] += h0 * wr[k] + h1 * wr[k + 1] + h2 * wr[k + 2] + h3 * wr[k + 3];
        }
    }
    const int i = i0 + lane;
#pragma unroll
    for (int c = 0; c < 8; ++c)
        whB[whb_idx(i, fb8 + c)] = f2bf(acc[c]);
}

// ---------------- Kernel B: s1'[i], s2'[i] = (Wh@a)*log2e --------------------
__global__ __launch_bounds__(256) void s_kernel(const unsigned short* __restrict__ whB,
                                                const float* __restrict__ a1,
                                                const float* __restrict__ a2,
                                                float* __restrict__ s1,
                                                float* __restrict__ s2) {
    __shared__ float p1[4][64], p2[4][64];
    const int t = threadIdx.x;
    const int l = t & 63;
    const int g = t >> 6;
    const int i = blockIdx.x * 64 + l;
    float acc1 = 0.f, acc2 = 0.f;
#pragma unroll
    for (int fb = g * 2; fb < g * 2 + 2; ++fb) {
#pragma unroll
        for (int sl = 0; sl < 16; ++sl) {
            int f = fb * 16 + sl;
            float v = bf2f(whB[whb_idx(i, f)]);
            acc1 += v * a1[f];
            acc2 += v * a2[f];
        }
    }
    p1[g][l] = acc1; p2[g][l] = acc2;
    __syncthreads();
    if (g == 0) {
        s1[i] = (p1[0][l] + p1[1][l] + p1[2][l] + p1[3][l]) * LOG2E;
        s2[i] = (p2[0][l] + p2[1][l] + p2[2][l] + p2[3][l]) * LOG2E;
    }
}

// ---------------- Kernel C: BARRIER-FREE bitmask gat -------------------------
// Wave owns 32 rows x JW cols in registers; adj comes from the 8 MB bitmask
// (L2/L3-resident): 2 mask bytes/lane/chunk instead of 64 B. No LDS, no
// __syncthreads. Grid 512 blocks x 4 waves = 8 waves/CU.
__global__ __launch_bounds__(256) void gat_kernel(const unsigned char* __restrict__ bits8,
                                                  const unsigned short* __restrict__ whB,
                                                  const float* __restrict__ s1,
                                                  const float* __restrict__ s2,
                                                  float* __restrict__ out,     // slice-0 num
                                                  float* __restrict__ nums,    // slices 1..7
                                                  float* __restrict__ dens) {  // 8 x N
    const int t = threadIdx.x;
    const int w = t >> 6;
    const int lane = t & 63;
    const int sl = lane & 15;
    const int quad = lane >> 4;
    const int slice = blockIdx.x & (JS - 1);
    const int rg = (blockIdx.x >> 3) * 4 + w;        // 0..255 row-group
    const int row0 = rg * 32;
    const int jb = slice * JW;
    float* __restrict__ num = slice ? (nums + (size_t)(slice - 1) * N_NODES * FOUT) : out;
    float* __restrict__ den = dens + (size_t)slice * N_NODES;

    const float s1a = s1[row0 + sl];                 // row of m-tile 0
    const float s1b = s1[row0 + 16 + sl];            // row of m-tile 1
    // mask bytes: row (row0+sl), byte (jb + ch*32 + quad*8)/8 = jb/8 + ch*4 + quad
    const unsigned char* bR0 = bits8 + (size_t)(row0 + sl) * (N_NODES / 8) + (jb >> 3) + quad;
    const unsigned char* bR1 = bR0 + (size_t)16 * (N_NODES / 8);
    const float* s2p = s2 + jb + quad * 8;

    f32x4 acc[2][8];
#pragma unroll
    for (int m = 0; m < 2; ++m)
#pragma unroll
        for (int fb = 0; fb < 8; ++fb) acc[m][fb] = (f32x4){0.f, 0.f, 0.f, 0.f};

    float d0 = 0.f, d1 = 0.f;

    // register prefetch, depth 1 (no barriers -> loads fly across iterations)
    unsigned int pm0 = bR0[0];
    unsigned int pm1 = bR1[0];
    f32x4 ps0 = *(const f32x4*)(s2p);
    f32x4 ps1 = *(const f32x4*)(s2p + 4);

#pragma unroll 1
    for (int ch = 0; ch < KCH; ++ch) {
        unsigned int cm0 = pm0, cm1 = pm1;
        f32x4 cs0 = ps0, cs1 = ps1;
        if (ch + 1 < KCH) {
            int o = (ch + 1) * 32;
            pm0 = bR0[(ch + 1) * 4];
            pm1 = bR1[(ch + 1) * 4];
            ps0 = *(const f32x4*)(s2p + o);
            ps1 = *(const f32x4*)(s2p + o + 4);
        }
        const int kb = jb / 32 + ch;
        const unsigned short* bp = whB + ((size_t)(kb * 8) << 9) + lane * 8;
        // ---- B group 0 issued before P-build (latency overlaps VALU) ----
        bf16x8 Ba[4];
#pragma unroll
        for (int fb = 0; fb < 4; ++fb) Ba[fb] = *(const bf16x8*)(bp + ((size_t)fb << 9));
        // ---- P in A-frag layout: lane holds P[sl][quad*8+e], e=0..7 ----
        float p0[8], p1[8];
#pragma unroll
        for (int e = 0; e < 8; ++e) {
            float sc = (e < 4) ? cs0[e] : cs1[e - 4];
            float y0 = s1a + sc;
            float y1 = s1b + sc;
            y0 = fmaxf(y0, 0.2f * y0);               // leaky (exp2 domain)
            y1 = fmaxf(y1, 0.2f * y1);
            float e0 = __builtin_amdgcn_exp2f(y0);
            float e1 = __builtin_amdgcn_exp2f(y1);
            p0[e] = ((cm0 >> e) & 1u) ? e0 : 0.f;
            p1[e] = ((cm1 >> e) & 1u) ? e1 : 0.f;
            d0 += p0[e];
            d1 += p1[e];
        }
        union { bf16x8 v; unsigned int u[4]; } A0, A1;
#pragma unroll
        for (int q = 0; q < 4; ++q) {
            A0.u[q] = pack_bf16(p0[2 * q], p0[2 * q + 1]);
            A1.u[q] = pack_bf16(p1[2 * q], p1[2 * q + 1]);
        }
        // ---- MFMA group 0 ----
#pragma unroll
        for (int fb = 0; fb < 4; ++fb) {
            acc[0][fb] = __builtin_amdgcn_mfma_f32_16x16x32_bf16(A0.v, Ba[fb], acc[0][fb], 0, 0, 0);
            acc[1][fb] = __builtin_amdgcn_mfma_f32_16x16x32_bf16(A1.v, Ba[fb], acc[1][fb], 0, 0, 0);
        }
        // ---- B group 1 + MFMA group 1 ----
        bf16x8 Bb[4];
#pragma unroll
        for (int fb = 0; fb < 4; ++fb) Bb[fb] = *(const bf16x8*)(bp + ((size_t)(4 + fb) << 9));
#pragma unroll
        for (int fb = 0; fb < 4; ++fb) {
            acc[0][4 + fb] = __builtin_amdgcn_mfma_f32_16x16x32_bf16(A0.v, Bb[fb], acc[0][4 + fb], 0, 0, 0);
            acc[1][4 + fb] = __builtin_amdgcn_mfma_f32_16x16x32_bf16(A1.v, Bb[fb], acc[1][4 + fb], 0, 0, 0);
        }
    }
    // ---- denominator: reduce across quads (lanes sl, sl+16, sl+32, sl+48) ----
    d0 += __shfl_xor(d0, 16); d0 += __shfl_xor(d0, 32);
    d1 += __shfl_xor(d1, 16); d1 += __shfl_xor(d1, 32);
    if (lane < 16) {
        den[row0 + lane] = d0;
        den[row0 + 16 + lane] = d1;
    }
    // ---- epilogue: raw partials (divide + ELU in fin_kernel) ----
#pragma unroll
    for (int m = 0; m < 2; ++m)
#pragma unroll
        for (int fb = 0; fb < 8; ++fb)
#pragma unroll
            for (int r = 0; r < 4; ++r) {
                int row = row0 + m * 16 + quad * 4 + r;   // D: row=quad*4+r, col=sl
                num[(size_t)row * FOUT + fb * 16 + sl] = acc[m][fb][r];
            }
}

// ---------------- Kernel D: merge 8 slices, divide, ELU (in-place) -----------
__global__ __launch_bounds__(256) void fin_kernel(float* __restrict__ out,      // = num0
                                                  const float* __restrict__ nums,
                                                  const float* __restrict__ dens) {
    const int idx = blockIdx.x * 256 + threadIdx.x;
    const int i = idx >> 7;                         // FOUT = 128
    const size_t NF = (size_t)N_NODES * FOUT;
    float numv = out[idx];
#pragma unroll
    for (int k = 0; k < JS - 1; ++k) numv += nums[k * NF + idx];
    float denv = 0.f;
#pragma unroll
    for (int k = 0; k < JS; ++k) denv += dens[k * N_NODES + i];
    float v = numv / fmaxf(denv, 1e-30f);
    out[idx] = (v > 0.f) ? v : expm1f(v);
}

extern "C" void kernel_launch(void* const* d_in, const int* in_sizes, int n_in,
                              void* d_out, int out_size, void* d_ws, size_t ws_size,
                              hipStream_t stream) {
    const float* h   = (const float*)d_in[0];
    const int*   adj = (const int*)d_in[1];
    const float* W   = (const float*)d_in[2];
    const float* a1  = (const float*)d_in[3];
    const float* a2  = (const float*)d_in[4];

    // d_ws layout (~45 MB used):
    //   [0, 2MB)    whB (bf16, fragment-ordered)
    //   [2, 10MB)   bitmask (8192 rows x 128 u64)
    //   [10MB..)    s1 | s2 | dens(8xN) | nums(7 x N*FOUT)
    char* ws = (char*)d_ws;
    unsigned short*     whB  = (unsigned short*)ws;
    unsigned long long* bits = (unsigned long long*)(ws + (2u << 20));
    float* s1   = (float*)(ws + (10u << 20));
    float* s2   = s1 + N_NODES;
    float* dens = s2 + N_NODES;
    float* nums = dens + JS * N_NODES;
    float* out  = (float*)d_out;

    pack_kernel<<<dim3(1024), 256, 0, stream>>>(adj, bits);
    wh_kernel<<<dim3(N_NODES / 64, FOUT / 32), 256, 0, stream>>>(h, W, whB);
    s_kernel<<<dim3(N_NODES / 64), 256, 0, stream>>>(whB, a1, a2, s1, s2);
    gat_kernel<<<dim3((N_NODES / 128) * JS), 256, 0, stream>>>((const unsigned char*)bits,
                                                               whB, s1, s2, out,
                                                               nums, dens);
    fin_kernel<<<dim3(N_NODES * FOUT / 256), 256, 0, stream>>>(out, nums, dens);
}

// Round 13
// 440.286 us; speedup vs baseline: 1.0118x; 1.0118x over previous
//
#include <hip/hip_runtime.h>
#include <cstdint>
#include <cstddef>

// Dtypes PROVEN fp32 (R2 bf16-read -> NaN; R4 fp32-read -> pass, absmax 0.0078).
#define N_NODES 8192
#define FIN 256
#define FOUT 128
#define JS 8                  // j slices (partial softmax, merged in fin_kernel)
#define JW (N_NODES / JS)     // 1024 columns per slice
#define KCH (JW / 32)         // 32 k-chunks of 32 cols
#define LOG2E 1.4426950408889634f

typedef __attribute__((ext_vector_type(8))) short bf16x8;
typedef __attribute__((ext_vector_type(4))) float f32x4;

__device__ __forceinline__ float bf2f(unsigned short u) {
    union { unsigned int i; float f; } v; v.i = ((unsigned int)u) << 16; return v.f;
}
__device__ __forceinline__ unsigned short f2bf(float f) {
    union { float f; unsigned int i; } v; v.f = f;
    unsigned int r = (v.i + 0x7FFFu + ((v.i >> 16) & 1u)) >> 16;
    return (unsigned short)r;
}
__device__ __forceinline__ unsigned int pack_bf16(float a, float b) {
    return (unsigned)f2bf(a) | ((unsigned)f2bf(b) << 16);
}

// async global->LDS, 16 B per lane; LDS dest = uniform base + lane*16
__device__ __forceinline__ void stage16(const unsigned short* g, unsigned short* l) {
    __builtin_amdgcn_global_load_lds(
        (const __attribute__((address_space(1))) unsigned int*)g,
        (__attribute__((address_space(3))) unsigned int*)l, 16, 0, 0);
}

// whB fragment-order layout: tile (kb, fb) holds Wh[j=kb*32+quad*8+e][f=fb*16+sl]
// at element ((kb*8+fb)*512 + (quad*16+sl)*8 + e) -> one contiguous 1 KB per wave.
__device__ __forceinline__ size_t whb_idx(int j, int f) {
    return ((size_t)((j >> 5) * 8 + (f >> 4)) << 9) + (((j >> 3) & 3) << 7)
         + ((f & 15) << 3) + (j & 7);
}

// ------------- Kernel P: pack adj -> TRANSPOSED bitmask bitsT32[w32][row] ----
// w32 covers cols [w32*32, w32*32+32), bit b <-> col w32*32+b. Column-major so
// a gat wave-load of 16 consecutive rows at one w32 is ONE 64/128B line.
__global__ __launch_bounds__(256) void pack_kernel(const int* __restrict__ adj,
                                                   unsigned int* __restrict__ bitsT) {
    const int t = threadIdx.x;
    const int lane = t & 63;
    const int wv = t >> 6;
    const int task = blockIdx.x * 4 + wv;           // 0..16383
    const int w = task & 127;                       // 64-col window
    const int r0 = (task >> 7) * 64;                // 64-row block
    const int* ap = adj + (size_t)r0 * N_NODES + w * 64 + lane;
    unsigned long long keep = 0;
#pragma unroll
    for (int r = 0; r < 64; ++r) {
        unsigned long long m = __ballot(ap[(size_t)r * N_NODES] > 0);
        if (lane == r) keep = m;                    // lane r holds row r0+r's 64 bits
    }
    // coalesced: lanes = consecutive rows
    bitsT[(size_t)(2 * w) * N_NODES + r0 + lane]     = (unsigned int)keep;
    bitsT[(size_t)(2 * w + 1) * N_NODES + r0 + lane] = (unsigned int)(keep >> 32);
}

// ---------------- Kernel A: whB = fragment-ordered bf16 (h @ W^T) -------------
__global__ __launch_bounds__(256) void wh_kernel(const float* __restrict__ h,
                                                 const float* __restrict__ W,
                                                 unsigned short* __restrict__ whB) {
    __shared__ float hT[64][FIN + 5];   // stride 261 (odd)
    const int t = threadIdx.x;
    const int i0 = blockIdx.x * 64;
    const int f0 = blockIdx.y * 32;
#pragma unroll
    for (int c = 0; c < 16; ++c) {       // 64x256 floats, float4-coalesced
        int chunk = c * 256 + t;
        int row = chunk >> 6, col = (chunk & 63) * 4;
        f32x4 v = *(const f32x4*)&h[(size_t)(i0 + row) * FIN + col];
        hT[row][col] = v[0]; hT[row][col + 1] = v[1];
        hT[row][col + 2] = v[2]; hT[row][col + 3] = v[3];
    }
    __syncthreads();
    const int lane = t & 63;
    const int fb8 = __builtin_amdgcn_readfirstlane(f0 + (t >> 6) * 8); // wave -> 8 f
    const float* w0 = W + (size_t)fb8 * FIN;
    float acc[8] = {0.f, 0.f, 0.f, 0.f, 0.f, 0.f, 0.f, 0.f};
    for (int k = 0; k < FIN; k += 4) {
        float h0 = hT[lane][k],     h1 = hT[lane][k + 1];
        float h2 = hT[lane][k + 2], h3 = hT[lane][k + 3];
#pragma unroll
        for (int c = 0; c < 8; ++c) {
            const float* wr = w0 + c * FIN;   // uniform -> s_load
            acc[c] += h0 * wr[k] + h1 * wr[k + 1] + h2 * wr[k + 2] + h3 * wr[k + 3];
        }
    }
    const int i = i0 + lane;
#pragma unroll
    for (int c = 0; c < 8; ++c)
        whB[whb_idx(i, fb8 + c)] = f2bf(acc[c]);
}

// ---------------- Kernel B: s1'[i], s2'[i] = (Wh@a)*log2e --------------------
__global__ __launch_bounds__(256) void s_kernel(const unsigned short* __restrict__ whB,
                                                const float* __restrict__ a1,
                                                const float* __restrict__ a2,
                                                float* __restrict__ s1,
                                                float* __restrict__ s2) {
    __shared__ float p1[4][64], p2[4][64];
    const int t = threadIdx.x;
    const int l = t & 63;
    const int g = t >> 6;
    const int i = blockIdx.x * 64 + l;
    float acc1 = 0.f, acc2 = 0.f;
#pragma unroll
    for (int fb = g * 2; fb < g * 2 + 2; ++fb) {
#pragma unroll
        for (int sl = 0; sl < 16; ++sl) {
            int f = fb * 16 + sl;
            float v = bf2f(whB[whb_idx(i, f)]);
            acc1 += v * a1[f];
            acc2 += v * a2[f];
        }
    }
    p1[g][l] = acc1; p2[g][l] = acc2;
    __syncthreads();
    if (g == 0) {
        s1[i] = (p1[0][l] + p1[1][l] + p1[2][l] + p1[3][l]) * LOG2E;
        s2[i] = (p2[0][l] + p2[1][l] + p2[2][l] + p2[3][l]) * LOG2E;
    }
}

// ---------------- Kernel C: transaction-minimized gat ------------------------
// Block = 4 waves = 128 rows, one j-slice. whB chunk (8 KB) staged ONCE per
// block via global_load_lds double-buffer (stage ch+1 after the barrier ->
// latency flies across chunk-ch compute). bits: 1 line/chunk (transposed).
// Per-chunk lines/wave: ~16 (whB shared) + 2 (bits) + 1 (s2) vs 104 in R12.
__global__ __launch_bounds__(256) void gat_kernel(const unsigned int* __restrict__ bitsT,
                                                  const unsigned short* __restrict__ whB,
                                                  const float* __restrict__ s1,
                                                  const float* __restrict__ s2,
                                                  float* __restrict__ out,     // slice-0 num
                                                  float* __restrict__ nums,    // slices 1..7
                                                  float* __restrict__ dens) {  // 8 x N
    __shared__ __align__(16) unsigned short lbuf[2][4096];   // 2 x 8 KB
    const int t = threadIdx.x;
    const int w = t >> 6;
    const int lane = t & 63;
    const int sl = lane & 15;
    const int quad = lane >> 4;
    const int slice = blockIdx.x & (JS - 1);
    const int rb = blockIdx.x >> 3;                  // 0..63 row-block (128 rows)
    const int row0 = rb * 128 + w * 32;              // this wave's 32 rows
    const int jb = slice * JW;
    const int kb0 = slice * KCH;
    float* __restrict__ num = slice ? (nums + (size_t)(slice - 1) * N_NODES * FOUT) : out;
    float* __restrict__ den = dens + (size_t)slice * N_NODES;

    const float s1a = s1[row0 + sl];
    const float s1b = s1[row0 + 16 + sl];
    // transposed bits: [w32][row]; per chunk one u32 per row
    const unsigned int* bT = bitsT + (size_t)(jb >> 5) * N_NODES;
    const float* s2p = s2 + jb + quad * 8;

    f32x4 acc[2][8];
#pragma unroll
    for (int m = 0; m < 2; ++m)
#pragma unroll
        for (int fb = 0; fb < 8; ++fb) acc[m][fb] = (f32x4){0.f, 0.f, 0.f, 0.f};
    float d0 = 0.f, d1 = 0.f;

    // preload chunk 0: stage whB tiles (wave w -> tiles 2w, 2w+1) + regs
    {
        const unsigned short* gt = whB + ((size_t)((kb0) * 8 + 2 * w) << 9);
        stage16(gt + lane * 8, &lbuf[0][2 * w * 512]);
        stage16(gt + 512 + lane * 8, &lbuf[0][(2 * w + 1) * 512]);
    }
    unsigned int m0 = bT[(size_t)0 * N_NODES + row0 + sl];
    unsigned int m1 = bT[(size_t)0 * N_NODES + row0 + 16 + sl];
    f32x4 sv0 = *(const f32x4*)(s2p);
    f32x4 sv1 = *(const f32x4*)(s2p + 4);

#pragma unroll 1
    for (int ch = 0; ch < KCH; ++ch) {
        __syncthreads();    // drains this wave's stage(ch)+regs(ch); syncs block
        unsigned int cm0 = m0 >> (quad * 8);
        unsigned int cm1 = m1 >> (quad * 8);
        f32x4 cs0 = sv0, cs1 = sv1;
        if (ch + 1 < KCH) {
            // stage ch+1 into the other buffer; completes by the NEXT barrier
            const unsigned short* gt = whB + ((size_t)((kb0 + ch + 1) * 8 + 2 * w) << 9);
            unsigned short* lb = &lbuf[(ch + 1) & 1][0];
            stage16(gt + lane * 8, lb + 2 * w * 512);
            stage16(gt + 512 + lane * 8, lb + (2 * w + 1) * 512);
            m0 = bT[(size_t)(ch + 1) * N_NODES + row0 + sl];
            m1 = bT[(size_t)(ch + 1) * N_NODES + row0 + 16 + sl];
            int o = (ch + 1) * 32;
            sv0 = *(const f32x4*)(s2p + o);
            sv1 = *(const f32x4*)(s2p + o + 4);
        }
        // ---- P in A-frag layout: lane holds P[sl][quad*8+e], e=0..7 ----
        float p0[8], p1[8];
#pragma unroll
        for (int e = 0; e < 8; ++e) {
            float sc = (e < 4) ? cs0[e] : cs1[e - 4];
            float y0 = s1a + sc;
            float y1 = s1b + sc;
            y0 = fmaxf(y0, 0.2f * y0);               // leaky (exp2 domain)
            y1 = fmaxf(y1, 0.2f * y1);
            float e0 = __builtin_amdgcn_exp2f(y0);
            float e1 = __builtin_amdgcn_exp2f(y1);
            p0[e] = ((cm0 >> e) & 1u) ? e0 : 0.f;
            p1[e] = ((cm1 >> e) & 1u) ? e1 : 0.f;
            d0 += p0[e];
            d1 += p1[e];
        }
        union { bf16x8 v; unsigned int u[4]; } A0, A1;
#pragma unroll
        for (int q = 0; q < 4; ++q) {
            A0.u[q] = pack_bf16(p0[2 * q], p0[2 * q + 1]);
            A1.u[q] = pack_bf16(p1[2 * q], p1[2 * q + 1]);
        }
        // ---- MFMA from LDS-shared B tiles ----
        const unsigned short* lb = &lbuf[ch & 1][0];
#pragma unroll
        for (int fb = 0; fb < 8; ++fb) {
            bf16x8 B = *(const bf16x8*)(lb + fb * 512 + lane * 8);  // ds_read_b128
            acc[0][fb] = __builtin_amdgcn_mfma_f32_16x16x32_bf16(A0.v, B, acc[0][fb], 0, 0, 0);
            acc[1][fb] = __builtin_amdgcn_mfma_f32_16x16x32_bf16(A1.v, B, acc[1][fb], 0, 0, 0);
        }
    }
    // ---- denominator: reduce across quads ----
    d0 += __shfl_xor(d0, 16); d0 += __shfl_xor(d0, 32);
    d1 += __shfl_xor(d1, 16); d1 += __shfl_xor(d1, 32);
    if (lane < 16) {
        den[row0 + lane] = d0;
        den[row0 + 16 + lane] = d1;
    }
    // ---- epilogue: raw partials (divide + ELU in fin_kernel) ----
#pragma unroll
    for (int m = 0; m < 2; ++m)
#pragma unroll
        for (int fb = 0; fb < 8; ++fb)
#pragma unroll
            for (int r = 0; r < 4; ++r) {
                int row = row0 + m * 16 + quad * 4 + r;   // D: row=quad*4+r, col=sl
                num[(size_t)row * FOUT + fb * 16 + sl] = acc[m][fb][r];
            }
}

// ---------------- Kernel D: merge 8 slices, divide, ELU (in-place) -----------
__global__ __launch_bounds__(256) void fin_kernel(float* __restrict__ out,      // = num0
                                                  const float* __restrict__ nums,
                                                  const float* __restrict__ dens) {
    const int idx = blockIdx.x * 256 + threadIdx.x;
    const int i = idx >> 7;                         // FOUT = 128
    const size_t NF = (size_t)N_NODES * FOUT;
    float numv = out[idx];
#pragma unroll
    for (int k = 0; k < JS - 1; ++k) numv += nums[k * NF + idx];
    float denv = 0.f;
#pragma unroll
    for (int k = 0; k < JS; ++k) denv += dens[k * N_NODES + i];
    float v = numv / fmaxf(denv, 1e-30f);
    out[idx] = (v > 0.f) ? v : expm1f(v);
}

extern "C" void kernel_launch(void* const* d_in, const int* in_sizes, int n_in,
                              void* d_out, int out_size, void* d_ws, size_t ws_size,
                              hipStream_t stream) {
    const float* h   = (const float*)d_in[0];
    const int*   adj = (const int*)d_in[1];
    const float* W   = (const float*)d_in[2];
    const float* a1  = (const float*)d_in[3];
    const float* a2  = (const float*)d_in[4];

    // d_ws layout (~45 MB used):
    //   [0, 2MB)    whB (bf16, fragment-ordered)
    //   [2, 10MB)   bitsT (256 col-words x 8192 rows, u32)
    //   [10MB..)    s1 | s2 | dens(8xN) | nums(7 x N*FOUT)
    char* ws = (char*)d_ws;
    unsigned short* whB   = (unsigned short*)ws;
    unsigned int*   bitsT = (unsigned int*)(ws + (2u << 20));
    float* s1   = (float*)(ws + (10u << 20));
    float* s2   = s1 + N_NODES;
    float* dens = s2 + N_NODES;
    float* nums = dens + JS * N_NODES;
    float* out  = (float*)d_out;

    pack_kernel<<<dim3(4096), 256, 0, stream>>>(adj, bitsT);
    wh_kernel<<<dim3(N_NODES / 64, FOUT / 32), 256, 0, stream>>>(h, W, whB);
    s_kernel<<<dim3(N_NODES / 64), 256, 0, stream>>>(whB, a1, a2, s1, s2);
    gat_kernel<<<dim3(64 * JS), 256, 0, stream>>>(bitsT, whB, s1, s2, out, nums, dens);
    fin_kernel<<<dim3(N_NODES * FOUT / 256), 256, 0, stream>>>(out, nums, dens);
}